// Round 4
// baseline (106.815 us; speedup 1.0000x reference)
//
#include <hip/hip_runtime.h>
#include <stdint.h>

// QuantizedPatternMatcher — R19: bitplane popcount with an explicit
// half-pattern software pipeline (the R15-proven prefetch shape).
//
// R18 post-mortem: match ~49us (headline-decomposed; below the 42us fill
// cutoff so no direct counters). Single-buffer sp[48] + unroll 1 =>
// [issue 12 loads][wait lgkmcnt(0) — SMEM returns unordered, so the wait
// drains EVERYTHING][192cyc VALU] per iteration: no pipelining, ~37% VALU
// duty, and pc fast-varying made neighboring CUs stream 32 different 6KB
// tiles through shared caches (correlated first-touch stalls).
//
// R19:
//  - A[24]/B[24] double-buffer at half-pattern granularity; loads for the
//    next half are issued BEFORE computing the current half, so the
//    compiler's waitcnt at first-use is covered by ~100cyc of VALU. Live
//    set rp48+A24+B24+misc ~= 105 < 128 => no spill, 4 waves/SIMD.
//  - pc = blockIdx>>5 (slow-varying): 32 consecutive blocks share one 6KB
//    pattern tile -> L1/L2-hot; xplanes L3-resident across pc sweeps.
//  - Last iteration over-reads 96B into the keys array (valid ws, unused).
// Inner loop per pattern: 12 uniform 16B loads + 96 int VALU (3 xor + 2 or
// + 1 bcnt-accum per 32-dim chunk). Chip VALU floor ~10.9us.
// Argmax = min-key (mis<<10)|pat via atomicMin (exact ref tie-break: max
// matches then lowest pattern index). Integer-exact end to end.
#define NROW 8192
#define NPAT 1024

typedef unsigned int u32;

__device__ __forceinline__ u32 bin7(float v, float e0, float e1, float e2,
                                    float e3, float e4, float e5, float e6) {
  return (u32)((v > e0) + (v > e1) + (v > e2) + (v > e3) + (v > e4) +
               (v > e5) + (v > e6));
}

__device__ __forceinline__ void acc3(u32 b, int k, u32& p0, u32& p1, u32& p2) {
  p0 |= (b & 1u) << k;
  p1 |= ((b >> 1) & 1u) << k;
  p2 |= ((b >> 2) & 1u) << k;
}

// ---------------------------------------------------------------------------
// prep: quantize + pack bitplanes.
//   xplanes [8192][16][3] u32   (48 dwords = 192 B per row; per 32-dim chunk
//   pplanes [1024][16][3] u32    the 3 planes are contiguous)
//   keys    [8192] u32 = 0xFFFFFFFF  (atomicMin targets; ws re-poisoned
//                                     every iteration so must re-init)
// ---------------------------------------------------------------------------
__global__ __launch_bounds__(256) void prep_pc(
    const float* __restrict__ x, const float* __restrict__ patterns,
    const float* __restrict__ edges, u32* __restrict__ xplanes,
    u32* __restrict__ pplanes, u32* __restrict__ keys) {
  const int bid = blockIdx.x, tid = threadIdx.x;
  if (bid >= 576) {  // 32 blocks: init keys
    const int r = (bid - 576) * 256 + tid;
    keys[r] = 0xFFFFFFFFu;
    return;
  }
  const float e0 = edges[0], e1 = edges[1], e2 = edges[2], e3 = edges[3],
              e4 = edges[4], e5 = edges[5], e6 = edges[6];
  const float4* s4;
  u32* dst;
  if (bid < 512) {  // x: 8192 rows * 16 chunks = 131072 threads
    const int i = bid * 256 + tid;  // i = row*16 + chunk
    s4 = reinterpret_cast<const float4*>(x + (size_t)i * 32);
    dst = xplanes + (size_t)i * 3;
  } else {  // patterns: 1024 * 16 = 16384 threads
    const int j = (bid - 512) * 256 + tid;
    s4 = reinterpret_cast<const float4*>(patterns + (size_t)j * 32);
    dst = pplanes + (size_t)j * 3;
  }
  u32 p0 = 0, p1 = 0, p2 = 0;
#pragma unroll
  for (int q = 0; q < 8; ++q) {
    const float4 a = s4[q];
    acc3(bin7(a.x, e0, e1, e2, e3, e4, e5, e6), q * 4 + 0, p0, p1, p2);
    acc3(bin7(a.y, e0, e1, e2, e3, e4, e5, e6), q * 4 + 1, p0, p1, p2);
    acc3(bin7(a.z, e0, e1, e2, e3, e4, e5, e6), q * 4 + 2, p0, p1, p2);
    acc3(bin7(a.w, e0, e1, e2, e3, e4, e5, e6), q * 4 + 3, p0, p1, p2);
  }
  dst[0] = p0;
  dst[1] = p1;
  dst[2] = p2;
}

// Load 24 dwords (one half-pattern: 8 chunks x 3 planes) as 6 uint4.
__device__ __forceinline__ void loadhalf(u32 (&d)[24],
                                         const u32* __restrict__ s) {
#pragma unroll
  for (int j = 0; j < 6; ++j) {
    const uint4 v = *reinterpret_cast<const uint4*>(s + j * 4);
    d[j * 4 + 0] = v.x;
    d[j * 4 + 1] = v.y;
    d[j * 4 + 2] = v.z;
    d[j * 4 + 3] = v.w;
  }
}

// 8 chunks of XOR/OR/popc against rp[c0*3 .. c0*3+23]. 48 int VALU.
__device__ __forceinline__ u32 comp8(const u32 (&rp)[48], const u32 (&b)[24],
                                     int c0) {
  u32 mis = 0;
#pragma unroll
  for (int c = 0; c < 8; ++c) {
    const u32 d = (rp[(c0 + c) * 3 + 0] ^ b[c * 3 + 0]) |
                  (rp[(c0 + c) * 3 + 1] ^ b[c * 3 + 1]) |
                  (rp[(c0 + c) * 3 + 2] ^ b[c * 3 + 2]);
    mis += (u32)__popc(d);
  }
  return mis;
}

// ---------------------------------------------------------------------------
// match: grid 1024 = 32 pattern-tiles (SLOW index: 32 consecutive blocks
// share a 6KB tile) x 32 row-blocks (256 rows, thread=row). 256 thr =
// 4 waves; ~4 blocks/CU = 4 waves/SIMD. Row planes rp[48] in VGPRs.
// Pattern halves A[24]/B[24] double-buffered: issue next half's loads
// before computing current half -> load latency hidden under ~100cyc VALU.
// ---------------------------------------------------------------------------
__global__ __launch_bounds__(256) void match_pc(
    const u32* __restrict__ xplanes, const u32* __restrict__ pplanes,
    u32* __restrict__ keys) {
  const int tid = threadIdx.x;
  const int pc = blockIdx.x >> 5;  // pattern tile, 0..31 (slow-varying)
  const int rb = blockIdx.x & 31;  // row block, 0..31
  const int row = rb * 256 + tid;

  u32 rp[48];
  {
    const uint4* __restrict__ rs =
        reinterpret_cast<const uint4*>(xplanes + (size_t)row * 48);
#pragma unroll
    for (int j = 0; j < 12; ++j) {
      const uint4 v = rs[j];
      rp[j * 4 + 0] = v.x;
      rp[j * 4 + 1] = v.y;
      rp[j * 4 + 2] = v.z;
      rp[j * 4 + 3] = v.w;
    }
  }

  const u32* __restrict__ pp = pplanes + (size_t)pc * (32 * 48);
  u32 A[24], B[24];
  loadhalf(A, pp);  // prologue: half0 of pattern 0

  u32 best = 0xFFFFFFFFu;
  const u32 pb = (u32)(pc << 5);
#pragma unroll 1
  for (int p = 0; p < 32; ++p) {
    loadhalf(B, pp + p * 48 + 24);  // issue half1(p)
    u32 mis = comp8(rp, A, 0);      // compute half0(p) — covers B's latency
    loadhalf(A, pp + (p + 1) * 48);  // issue half0(p+1); p=31 over-reads
                                     // 96B into keys[] (valid ws, unused)
    mis += comp8(rp, B, 8);          // compute half1(p) — covers A's latency
    const u32 key = (mis << 10) | (pb + (u32)p);
    best = key < best ? key : best;
  }
  atomicMin(&keys[row], best);
}

__global__ __launch_bounds__(256) void fixup_pc(const u32* __restrict__ keys,
                                                float* __restrict__ out) {
  const int r = blockIdx.x * 256 + threadIdx.x;
  const u32 k = keys[r];
  out[r] = (float)(k & 1023u);
  out[NROW + r] = (float)(512u - (k >> 10)) * (1.0f / 512.0f);
}

extern "C" void kernel_launch(void* const* d_in, const int* in_sizes, int n_in,
                              void* d_out, int out_size, void* d_ws,
                              size_t ws_size, hipStream_t stream) {
  const float* x = (const float*)d_in[0];         // [8192, 512] f32
  const float* patterns = (const float*)d_in[1];  // [1024, 512] f32
  const float* edges = (const float*)d_in[2];     // [7] f32
  float* out = (float*)d_out;                     // 16384 f32

  u32* xplanes = (u32*)d_ws;                       // 1.57 MB
  u32* pplanes = xplanes + (size_t)NROW * 48;      // 196 KB
  u32* keys = pplanes + (size_t)NPAT * 48;         // 32 KB

  prep_pc<<<608, 256, 0, stream>>>(x, patterns, edges, xplanes, pplanes, keys);
  match_pc<<<1024, 256, 0, stream>>>(xplanes, pplanes, keys);
  fixup_pc<<<32, 256, 0, stream>>>(keys, out);
}